// Round 3
// baseline (294.394 us; speedup 1.0000x reference)
//
#include <hip/hip_runtime.h>

// B=4, Cin=64, Cout=128, H=W=128, 3x3, stride=1, pad=1, dil=1
#define HW    16384
#define NB    4
#define CIN   64
#define COUT  128

typedef short  short8  __attribute__((ext_vector_type(8)));
typedef float  floatx4 __attribute__((ext_vector_type(4)));

// fp32 -> bf16 round-to-nearest-even
__device__ __forceinline__ short f2b(float f) {
  unsigned u = __float_as_uint(f);
  u += 0x7fff + ((u >> 16) & 1);
  return (short)(u >> 16);
}

// ---------------------------------------------------------------------------
// k_prep: bf16 weight repack into TAP-MAJOR K order (ck' = tap*C + c).
//  wtb  [o][k*64+c]  = bf16(weight[o][c][k])   o<128, K=576
//  wtbom[o][k*128+c] = bf16(w_om[o][c][k])     o<27 (padded to 32), K=1152
// ---------------------------------------------------------------------------
__global__ __launch_bounds__(256) void k_prep(const float* __restrict__ weight,
                                              const float* __restrict__ w_om,
                                              short* __restrict__ wtb,
                                              short* __restrict__ wtbom) {
  int i = blockIdx.x * 256 + threadIdx.x;
  if (i < 128 * 576) {
    int o = i / 576, r = i - o * 576;
    int k = r >> 6, c = r & 63;
    wtb[i] = f2b(weight[o * 576 + c * 9 + k]);
  }
  if (i < 32 * 1152) {
    int o = i / 1152, r = i - o * 1152;
    int k = r >> 7, c = r & 127;
    wtbom[i] = (o < 27) ? f2b(w_om[o * 1152 + c * 9 + k]) : (short)0;
  }
}

// ---------------------------------------------------------------------------
// k_om: 3x3 conv (Cin=128 concat, Cout=27) via halo patch + bf16 MFMA.
// Block: 256 thr, 64-px row segment. Load 3x66 halo x 128ch ONCE into LDS
// (octet-major [g16][pxrow198][8ch], all b128 aligned), 1 barrier, then
// M=32 x N=64 x K=1152 MFMA reading tap-shifted B-fragments from the patch.
// ---------------------------------------------------------------------------
__global__ __launch_bounds__(256) void k_om(const float* __restrict__ xin,
                                            const float* __restrict__ inter,
                                            const short* __restrict__ wtbom,
                                            const float* __restrict__ b_om,
                                            float* __restrict__ om) {
  __shared__ __align__(16) short sP[16 * 198 * 8];   // 50688 B
  const int blk = blockIdx.x;
  const int b   = blk >> 8;
  const int hw0 = (blk & 255) * 64;
  const int h0  = hw0 >> 7;
  const int x0  = hw0 & 127;
  const int tid = threadIdx.x;
  const float* base0 = xin   + (size_t)b * CIN * HW;
  const float* base1 = inter + (size_t)b * CIN * HW;

  // ---- gather halo patch (3 rows x 66 cols x 128 ch), zero-padded ----
  for (int item = tid; item < 3168; item += 256) {   // 198 pxrows x 16 octets
    int g = item & 15, pxrow = item >> 4;
    int r3 = pxrow / 66, c66 = pxrow - r3 * 66;
    int y = h0 + r3 - 1;
    int x = x0 + c66 - 1;
    bool valid = ((unsigned)y < 128u) && ((unsigned)x < 128u);
    int sofs = valid ? (y * 128 + x) : 0;
    const float* pl = (g < 8) ? (base0 + g * 8 * HW) : (base1 + (g - 8) * 8 * HW);
    short8 pk;
#pragma unroll
    for (int i = 0; i < 8; ++i) {
      float v = valid ? pl[i * HW + sofs] : 0.f;
      pk[i] = f2b(v);
    }
    *(short8*)(&sP[(g * 198 + pxrow) * 8]) = pk;
  }
  __syncthreads();

  // ---- MFMA: M=32(o) x N=64(px) x K=1152, wave wv owns Ntile wv ----
  const int l15 = tid & 15, quad = (tid & 63) >> 4, wv = tid >> 6;
  floatx4 acc0 = {0.f, 0.f, 0.f, 0.f};
  floatx4 acc1 = {0.f, 0.f, 0.f, 0.f};
  for (int tap = 0; tap < 9; ++tap) {
    int prow = (tap / 3) * 66 + (tap % 3) + wv * 16 + l15;   // tap-shifted px row
#pragma unroll
    for (int ss = 0; ss < 4; ++ss) {
      int ka = l15 * 1152 + tap * 128 + ss * 32 + quad * 8;
      short8 a0 = *(const short8*)(&wtbom[ka]);
      short8 a1 = *(const short8*)(&wtbom[ka + 16 * 1152]);
      short8 bb = *(const short8*)(&sP[((ss * 4 + quad) * 198 + prow) * 8]);
      acc0 = __builtin_amdgcn_mfma_f32_16x16x32_bf16(a0, bb, acc0, 0, 0, 0);
      acc1 = __builtin_amdgcn_mfma_f32_16x16x32_bf16(a1, bb, acc1, 0, 0, 0);
    }
  }

  // ---- epilogue: D[row=o][col=px], store o<27 ----
  float* ob = om + (size_t)b * 27 * HW + hw0 + wv * 16 + l15;
#pragma unroll
  for (int r = 0; r < 4; ++r) {
    int o = quad * 4 + r;
    if (o < 27) ob[o * HW] = acc0[r] + b_om[o];
    int o1 = 16 + quad * 4 + r;
    if (o1 < 27) ob[o1 * HW] = acc1[r] + b_om[o1];
  }
}

// ---------------------------------------------------------------------------
// k_dcn: modulated deformable conv, bf16 MFMA GEMM.
// Block: 256 thr, 32-px tile, M=128(o) x N=32(px) x K=576.
// SINGLE gather phase: full 576-row V panel into LDS (octet-major
// [k/8][px][8ch], 36.9 KB, b128-aligned), 288 independent loads/thread,
// exactly 2 barriers per block, then uninterrupted 18-K-step MFMA loop.
// ---------------------------------------------------------------------------
__global__ __launch_bounds__(256) void k_dcn(const float* __restrict__ xin,
                                             const float* __restrict__ om,
                                             const short* __restrict__ wtb,
                                             const float* __restrict__ bias,
                                             float* __restrict__ out) {
  __shared__ __align__(16) short sV[72 * 32 * 8];   // 36864 B
  __shared__ float4 sW[9][32];                      //  4608 B
  __shared__ int4   sO[9][32];                      //  4608 B
  const int blk = blockIdx.x;
  const int b   = blk >> 9;
  const int hw0 = (blk & 511) * 32;
  const int tid = threadIdx.x;

  // ---- phase 0: bilinear params per (tap, px) ----
  for (int item = tid; item < 9 * 32; item += 256) {
    int k  = item >> 5;
    int px = item & 31;
    int hw = hw0 + px;
    int h = hw >> 7, w = hw & 127;
    const float* ob = om + (size_t)b * 27 * HW + hw;
    float dy = ob[(2 * k) * HW];
    float dx = ob[(2 * k + 1) * HW];
    float mr = ob[(18 + k) * HW];
    float m  = 1.f / (1.f + __expf(-mr));
    float py  = (float)(k / 3 - 1 + h) + dy;
    float pxx = (float)(k % 3 - 1 + w) + dx;
    float y0f = floorf(py), x0f = floorf(pxx);
    float fy = py - y0f, fx = pxx - x0f;
    int y0 = (int)y0f, x0 = (int)x0f;
    int y1 = y0 + 1, x1 = x0 + 1;
    float vy0 = ((unsigned)y0 < 128u) ? 1.f : 0.f;
    float vy1 = ((unsigned)y1 < 128u) ? 1.f : 0.f;
    float vx0 = ((unsigned)x0 < 128u) ? 1.f : 0.f;
    float vx1 = ((unsigned)x1 < 128u) ? 1.f : 0.f;
    int yc0 = min(max(y0, 0), 127), yc1 = min(max(y1, 0), 127);
    int xc0 = min(max(x0, 0), 127), xc1 = min(max(x1, 0), 127);
    float gy0 = (1.f - fy) * m, gy1 = fy * m;
    sW[k][px] = make_float4(gy0 * (1.f - fx) * vy0 * vx0,
                            gy0 * fx         * vy0 * vx1,
                            gy1 * (1.f - fx) * vy1 * vx0,
                            gy1 * fx         * vy1 * vx1);
    sO[k][px] = make_int4(yc0 * 128 + xc0, yc0 * 128 + xc1,
                          yc1 * 128 + xc0, yc1 * 128 + xc1);
  }
  __syncthreads();

  // ---- gather: all 9 taps x 64 channels -> LDS bf16, no barriers inside ----
  const int px1 = tid & 31;
  const int g0  = tid >> 5;              // channel octet [0,8)
  const float* xb = xin + (size_t)b * CIN * HW;
  const float* p0 = xb + g0 * 8 * HW;
#pragma unroll 2
  for (int j = 0; j < 9; ++j) {
    float4 wv = sW[j][px1];
    int4   ov = sO[j][px1];
    short8 pk;
#pragma unroll
    for (int i = 0; i < 8; ++i) {
      const float* pc = p0 + i * HW;
      float v = wv.x * pc[ov.x] + wv.y * pc[ov.y] +
                wv.z * pc[ov.z] + wv.w * pc[ov.w];
      pk[i] = f2b(v);
    }
    *(short8*)(&sV[((j * 8 + g0) * 32 + px1) * 8]) = pk;
  }
  __syncthreads();

  // ---- MFMA: 18 K-steps, wave owns o [wave*32, wave*32+32) x all 32 px ----
  const int l15 = tid & 15, quad = (tid & 63) >> 4, wave = tid >> 6;
  const int ob0 = wave * 32;
  floatx4 acc00 = {0.f,0.f,0.f,0.f}, acc01 = {0.f,0.f,0.f,0.f};
  floatx4 acc10 = {0.f,0.f,0.f,0.f}, acc11 = {0.f,0.f,0.f,0.f};
#pragma unroll 6
  for (int s = 0; s < 18; ++s) {
    int ka = (ob0 + l15) * 576 + s * 32 + quad * 8;
    short8 a0 = *(const short8*)(&wtb[ka]);
    short8 a1 = *(const short8*)(&wtb[ka + 16 * 576]);
    short8 bb0 = *(const short8*)(&sV[((s * 4 + quad) * 32 + l15) * 8]);
    short8 bb1 = *(const short8*)(&sV[((s * 4 + quad) * 32 + 16 + l15) * 8]);
    acc00 = __builtin_amdgcn_mfma_f32_16x16x32_bf16(a0, bb0, acc00, 0, 0, 0);
    acc01 = __builtin_amdgcn_mfma_f32_16x16x32_bf16(a0, bb1, acc01, 0, 0, 0);
    acc10 = __builtin_amdgcn_mfma_f32_16x16x32_bf16(a1, bb0, acc10, 0, 0, 0);
    acc11 = __builtin_amdgcn_mfma_f32_16x16x32_bf16(a1, bb1, acc11, 0, 0, 0);
  }

  // ---- epilogue: D[row=o][col=px], coalesced 64B per quad ----
  float* outb = out + (size_t)b * COUT * HW + hw0;
#pragma unroll
  for (int r = 0; r < 4; ++r) {
    int o = ob0 + quad * 4 + r;
    float bo = bias[o];
    outb[(size_t)o * HW + l15]      = acc00[r] + bo;
    outb[(size_t)o * HW + 16 + l15] = acc01[r] + bo;
    int o1 = o + 16;
    float bo1 = bias[o1];
    outb[(size_t)o1 * HW + l15]      = acc10[r] + bo1;
    outb[(size_t)o1 * HW + 16 + l15] = acc11[r] + bo1;
  }
}

// ---------------------------------------------------------------------------
extern "C" void kernel_launch(void* const* d_in, const int* in_sizes, int n_in,
                              void* d_out, int out_size, void* d_ws, size_t ws_size,
                              hipStream_t stream) {
  const float* input_feat = (const float*)d_in[0];  // [4,64,128,128]
  const float* inter      = (const float*)d_in[1];  // [4,64,128,128]
  const float* weight     = (const float*)d_in[2];  // [128,64,3,3]
  const float* bias       = (const float*)d_in[3];  // [128]
  const float* w_om       = (const float*)d_in[4];  // [27,128,3,3]
  const float* b_om       = (const float*)d_in[5];  // [27]
  float* out = (float*)d_out;                       // [4,128,128,128]

  float* om    = (float*)d_ws;                           // 1769472 f32 (7.08 MB)
  short* wtb   = (short*)((char*)d_ws + 7077888);        // 73728 bf16
  short* wtbom = (short*)((char*)d_ws + 7225344);        // 36864 bf16

  k_prep<<<288, 256, 0, stream>>>(weight, w_om, wtb, wtbom);
  k_om<<<NB * (HW / 64), 256, 0, stream>>>(input_feat, inter, wtbom, b_om, om);
  k_dcn<<<NB * (HW / 32), 256, 0, stream>>>(input_feat, om, wtb, bias, out);
}

// Round 4
// 214.843 us; speedup vs baseline: 1.3703x; 1.3703x over previous
//
#include <hip/hip_runtime.h>
#include <hip/hip_fp16.h>

// B=4, Cin=64, Cout=128, H=W=128, 3x3, stride=1, pad=1, dil=1
#define HW    16384
#define NB    4
#define CIN   64
#define COUT  128

typedef short  short8  __attribute__((ext_vector_type(8)));
typedef float  floatx4 __attribute__((ext_vector_type(4)));

// fp32 -> bf16 round-to-nearest-even (returns raw bits)
__device__ __forceinline__ unsigned short f2b(float f) {
  unsigned u = __float_as_uint(f);
  u += 0x7fff + ((u >> 16) & 1);
  return (unsigned short)(u >> 16);
}
__device__ __forceinline__ unsigned packbf2(float lo, float hi) {
  return (unsigned)f2b(lo) | ((unsigned)f2b(hi) << 16);
}
__device__ __forceinline__ float bflo(unsigned u) { return __uint_as_float(u << 16); }
__device__ __forceinline__ float bfhi(unsigned u) { return __uint_as_float(u & 0xffff0000u); }
__device__ __forceinline__ unsigned packh2(float a, float b) {
  __half2 h = __floats2half2_rn(a, b);
  return *(unsigned*)&h;
}

// ---------------------------------------------------------------------------
// k_tr: CHW fp32 (x ++ inter) -> HWC bf16  xt[b][hw][128]
// Block: 256 thr, 64-px tile. Coalesced reads (lane=px), pair-packed LDS
// (stride 69 words -> conflict-free), uint4 stores (lane=ch-octet).
// ---------------------------------------------------------------------------
__global__ __launch_bounds__(256) void k_tr(const float* __restrict__ x,
                                            const float* __restrict__ inter,
                                            short* __restrict__ xt) {
  __shared__ unsigned sT[64][69];
  const int blk = blockIdx.x;
  const int b = blk >> 8, hw0 = (blk & 255) * 64;
  const int tid = threadIdx.x;
  const int px = tid & 63, cg = tid >> 6;
  const float* s0 = x     + (size_t)b * CIN * HW + hw0 + px;
  const float* s1 = inter + (size_t)b * CIN * HW + hw0 + px;
#pragma unroll
  for (int step = 0; step < 16; ++step) {
    int cp = step * 4 + cg;           // channel pair, c = 2*cp (even)
    int c = cp * 2;
    const float* s = (c < 64) ? (s0 + c * HW) : (s1 + (c - 64) * HW);
    sT[px][cp] = packbf2(s[0], s[HW]);
  }
  __syncthreads();
  const int oc = tid & 15;
#pragma unroll
  for (int it = 0; it < 4; ++it) {
    int p = (tid >> 4) + it * 16;
    uint4 o4;
    o4.x = sT[p][oc * 4 + 0]; o4.y = sT[p][oc * 4 + 1];
    o4.z = sT[p][oc * 4 + 2]; o4.w = sT[p][oc * 4 + 3];
    *(uint4*)(xt + ((size_t)b * HW + hw0 + p) * 128 + oc * 8) = o4;
  }
}

// ---------------------------------------------------------------------------
// k_prep: bf16 weight repack into TAP-MAJOR K order (ck' = tap*C + c).
// ---------------------------------------------------------------------------
__global__ __launch_bounds__(256) void k_prep(const float* __restrict__ weight,
                                              const float* __restrict__ w_om,
                                              short* __restrict__ wtb,
                                              short* __restrict__ wtbom) {
  int i = blockIdx.x * 256 + threadIdx.x;
  if (i < 128 * 576) {
    int o = i / 576, r = i - o * 576;
    int k = r >> 6, c = r & 63;
    wtb[i] = (short)f2b(weight[o * 576 + c * 9 + k]);
  }
  if (i < 32 * 1152) {
    int o = i / 1152, r = i - o * 1152;
    int k = r >> 7, c = r & 127;
    wtbom[i] = (o < 27) ? (short)f2b(w_om[o * 1152 + c * 9 + k]) : (short)0;
  }
}

// ---------------------------------------------------------------------------
// k_om: 3x3 conv (Cin=128 concat, Cout=27) via halo patch + bf16 MFMA.
// Patch now sourced from xt (HWC bf16): pure uint4 copies, coalesced
// (lane = channel-octet: 16 lanes x 16B = one px's 256B row).
// ---------------------------------------------------------------------------
__global__ __launch_bounds__(256) void k_om(const short* __restrict__ xt,
                                            const short* __restrict__ wtbom,
                                            const float* __restrict__ b_om,
                                            float* __restrict__ om) {
  __shared__ __align__(16) short sP[16 * 198 * 8];   // 50688 B
  const int blk = blockIdx.x;
  const int b   = blk >> 8;
  const int hw0 = (blk & 255) * 64;
  const int h0  = hw0 >> 7;
  const int x0  = hw0 & 127;
  const int tid = threadIdx.x;
  const short* xtb = xt + (size_t)b * HW * 128;

  // ---- gather halo patch (3 rows x 66 cols x 128 ch), zero-padded ----
  for (int item = tid; item < 3168; item += 256) {   // lane: g fastest
    int g = item & 15, pxrow = item >> 4;
    int r3 = pxrow / 66, c66 = pxrow - r3 * 66;
    int y = h0 + r3 - 1;
    int x = x0 + c66 - 1;
    uint4 v = make_uint4(0, 0, 0, 0);
    if (((unsigned)y < 128u) && ((unsigned)x < 128u))
      v = *(const uint4*)(xtb + ((size_t)(y * 128 + x)) * 128 + g * 8);
    *(uint4*)(&sP[(g * 198 + pxrow) * 8]) = v;
  }
  __syncthreads();

  // ---- MFMA: M=32(o) x N=64(px) x K=1152, wave wv owns Ntile wv ----
  const int l15 = tid & 15, quad = (tid & 63) >> 4, wv = tid >> 6;
  floatx4 acc0 = {0.f, 0.f, 0.f, 0.f};
  floatx4 acc1 = {0.f, 0.f, 0.f, 0.f};
  for (int tap = 0; tap < 9; ++tap) {
    int prow = (tap / 3) * 66 + (tap % 3) + wv * 16 + l15;   // tap-shifted px row
#pragma unroll
    for (int ss = 0; ss < 4; ++ss) {
      int ka = l15 * 1152 + tap * 128 + ss * 32 + quad * 8;
      short8 a0 = *(const short8*)(&wtbom[ka]);
      short8 a1 = *(const short8*)(&wtbom[ka + 16 * 1152]);
      short8 bb = *(const short8*)(&sP[((ss * 4 + quad) * 198 + prow) * 8]);
      acc0 = __builtin_amdgcn_mfma_f32_16x16x32_bf16(a0, bb, acc0, 0, 0, 0);
      acc1 = __builtin_amdgcn_mfma_f32_16x16x32_bf16(a1, bb, acc1, 0, 0, 0);
    }
  }

  // ---- epilogue: D[row=o][col=px], store o<27 ----
  float* ob = om + (size_t)b * 27 * HW + hw0 + wv * 16 + l15;
#pragma unroll
  for (int r = 0; r < 4; ++r) {
    int o = quad * 4 + r;
    if (o < 27) ob[o * HW] = acc0[r] + b_om[o];
    int o1 = 16 + quad * 4 + r;
    if (o1 < 27) ob[o1 * HW] = acc1[r] + b_om[o1];
  }
}

// ---------------------------------------------------------------------------
// k_dcn: modulated deformable conv, bf16 MFMA GEMM, HWC gather.
// Block: 256 thr, 32-px tile, M=128(o) x N=32(px) x K=576.
// Phase 0: per-(tap,px) params packed 12B (fp16 col-weights folded with
//          edge clamping + 2 ushort row offsets) into 3456B LDS.
// Gather:  thread (px, ch-octet): per tap 4 aligned dwordx4 corner loads,
//          bilinear in fp32, pack bf16, one ds_write_b128. No LDS deps
//          (params preloaded to regs) -> deep load pipelining.
// ---------------------------------------------------------------------------
__global__ __launch_bounds__(256, 4) void k_dcn(const short* __restrict__ xt,
                                                const float* __restrict__ om,
                                                const short* __restrict__ wtb,
                                                const float* __restrict__ bias,
                                                float* __restrict__ out) {
  __shared__ __align__(16) short sV[72 * 32 * 8];   // 36864 B
  __shared__ unsigned sPar[9 * 32 * 3];             //  3456 B  (total 40320)
  const int blk = blockIdx.x;
  const int b   = blk >> 9;
  const int hw0 = (blk & 511) * 32;
  const int tid = threadIdx.x;

  // ---- phase 0: packed bilinear params per (tap, px) ----
  for (int item = tid; item < 9 * 32; item += 256) {
    int k  = item >> 5;
    int px = item & 31;
    int hw = hw0 + px;
    int h = hw >> 7, w = hw & 127;
    const float* ob = om + (size_t)b * 27 * HW + hw;
    float dy = ob[(2 * k) * HW];
    float dx = ob[(2 * k + 1) * HW];
    float mr = ob[(18 + k) * HW];
    float m  = 1.f / (1.f + __expf(-mr));
    float py  = (float)(k / 3 - 1 + h) + dy;
    float pxx = (float)(k % 3 - 1 + w) + dx;
    float y0f = floorf(py), x0f = floorf(pxx);
    float fy = py - y0f, fx = pxx - x0f;
    int y0 = (int)y0f, x0 = (int)x0f;
    int y1 = y0 + 1, x1 = x0 + 1;
    float vy0 = ((unsigned)y0 < 128u) ? 1.f : 0.f;
    float vy1 = ((unsigned)y1 < 128u) ? 1.f : 0.f;
    float hx0 = ((unsigned)x0 < 128u) ? (1.f - fx) : 0.f;
    float hx1 = ((unsigned)x1 < 128u) ? fx : 0.f;
    int yc0 = min(max(y0, 0), 127), yc1 = min(max(y1, 0), 127);
    int xc0 = min(max(x0, 0), 127), xc1 = min(max(x1, 0), 127);
    int xb  = min(xc0, 126);
    // fold column clamping into physical-column weights (cols xb, xb+1)
    float wA = (xc0 == xb     ? hx0 : 0.f) + (xc1 == xb     ? hx1 : 0.f);
    float wB = (xc0 == xb + 1 ? hx0 : 0.f) + (xc1 == xb + 1 ? hx1 : 0.f);
    float gy0 = (1.f - fy) * vy0 * m, gy1 = fy * vy1 * m;
    int base = (k * 32 + px) * 3;
    sPar[base + 0] = packh2(gy0 * wA, gy0 * wB);
    sPar[base + 1] = packh2(gy1 * wA, gy1 * wB);
    sPar[base + 2] = (unsigned)(yc0 * 128 + xb) | ((unsigned)(yc1 * 128 + xb) << 16);
  }
  __syncthreads();

  // ---- gather: 9 taps x 8 channels per thread, HWC dwordx4 corners ----
  const int px1 = tid & 31;
  const int g0  = tid >> 5;              // channel octet [0,8)
  const short* xtb = xt + (size_t)b * HW * 128 + g0 * 8;

  unsigned pw0[9], pw1[9], pof[9];
#pragma unroll
  for (int j = 0; j < 9; ++j) {
    int base = (j * 32 + px1) * 3;
    pw0[j] = sPar[base + 0];
    pw1[j] = sPar[base + 1];
    pof[j] = sPar[base + 2];
  }

#pragma unroll 3
  for (int j = 0; j < 9; ++j) {
    float2 wy0 = __half22float2(*(__half2*)&pw0[j]);   // row y0: cols xb, xb+1
    float2 wy1 = __half22float2(*(__half2*)&pw1[j]);   // row y1
    int offA = pof[j] & 0xffff, offB = pof[j] >> 16;
    const short* pa = xtb + (size_t)offA * 128;
    const short* pb = xtb + (size_t)offB * 128;
    uint4 A = *(const uint4*)pa;
    uint4 Bv = *(const uint4*)(pa + 128);
    uint4 C = *(const uint4*)pb;
    uint4 D = *(const uint4*)(pb + 128);
    unsigned res[4];
    const unsigned* Au = (const unsigned*)&A;
    const unsigned* Bu = (const unsigned*)&Bv;
    const unsigned* Cu = (const unsigned*)&C;
    const unsigned* Du = (const unsigned*)&D;
#pragma unroll
    for (int d = 0; d < 4; ++d) {
      float vlo = bflo(Au[d]) * wy0.x + bflo(Bu[d]) * wy0.y +
                  bflo(Cu[d]) * wy1.x + bflo(Du[d]) * wy1.y;
      float vhi = bfhi(Au[d]) * wy0.x + bfhi(Bu[d]) * wy0.y +
                  bfhi(Cu[d]) * wy1.x + bfhi(Du[d]) * wy1.y;
      res[d] = packbf2(vlo, vhi);
    }
    *(uint4*)(&sV[((j * 8 + g0) * 32 + px1) * 8]) =
        make_uint4(res[0], res[1], res[2], res[3]);
  }
  __syncthreads();

  // ---- MFMA: 18 K-steps, wave owns o [wave*32, wave*32+32) x all 32 px ----
  const int l15 = tid & 15, quad = (tid & 63) >> 4, wave = tid >> 6;
  const int ob0 = wave * 32;
  floatx4 acc00 = {0.f,0.f,0.f,0.f}, acc01 = {0.f,0.f,0.f,0.f};
  floatx4 acc10 = {0.f,0.f,0.f,0.f}, acc11 = {0.f,0.f,0.f,0.f};
#pragma unroll 6
  for (int s = 0; s < 18; ++s) {
    int ka = (ob0 + l15) * 576 + s * 32 + quad * 8;
    short8 a0 = *(const short8*)(&wtb[ka]);
    short8 a1 = *(const short8*)(&wtb[ka + 16 * 576]);
    short8 bb0 = *(const short8*)(&sV[((s * 4 + quad) * 32 + l15) * 8]);
    short8 bb1 = *(const short8*)(&sV[((s * 4 + quad) * 32 + 16 + l15) * 8]);
    acc00 = __builtin_amdgcn_mfma_f32_16x16x32_bf16(a0, bb0, acc00, 0, 0, 0);
    acc01 = __builtin_amdgcn_mfma_f32_16x16x32_bf16(a0, bb1, acc01, 0, 0, 0);
    acc10 = __builtin_amdgcn_mfma_f32_16x16x32_bf16(a1, bb0, acc10, 0, 0, 0);
    acc11 = __builtin_amdgcn_mfma_f32_16x16x32_bf16(a1, bb1, acc11, 0, 0, 0);
  }

  // ---- epilogue ----
  float* outb = out + (size_t)b * COUT * HW + hw0;
#pragma unroll
  for (int r = 0; r < 4; ++r) {
    int o = ob0 + quad * 4 + r;
    float bo = bias[o];
    outb[(size_t)o * HW + l15]      = acc00[r] + bo;
    outb[(size_t)o * HW + 16 + l15] = acc01[r] + bo;
    int o1 = o + 16;
    float bo1 = bias[o1];
    outb[(size_t)o1 * HW + l15]      = acc10[r] + bo1;
    outb[(size_t)o1 * HW + 16 + l15] = acc11[r] + bo1;
  }
}

// ---------------------------------------------------------------------------
extern "C" void kernel_launch(void* const* d_in, const int* in_sizes, int n_in,
                              void* d_out, int out_size, void* d_ws, size_t ws_size,
                              hipStream_t stream) {
  const float* input_feat = (const float*)d_in[0];  // [4,64,128,128]
  const float* inter      = (const float*)d_in[1];  // [4,64,128,128]
  const float* weight     = (const float*)d_in[2];  // [128,64,3,3]
  const float* bias       = (const float*)d_in[3];  // [128]
  const float* w_om       = (const float*)d_in[4];  // [27,128,3,3]
  const float* b_om       = (const float*)d_in[5];  // [27]
  float* out = (float*)d_out;                       // [4,128,128,128]

  float* om    = (float*)d_ws;                           // 7077888 B
  short* wtb   = (short*)((char*)d_ws + 7077888);        // 147456 B
  short* wtbom = (short*)((char*)d_ws + 7225344);        // 73728 B
  short* xt    = (short*)((char*)d_ws + 7299072);        // 16777216 B (HWC bf16)

  k_tr<<<NB * (HW / 64), 256, 0, stream>>>(input_feat, inter, xt);
  k_prep<<<288, 256, 0, stream>>>(weight, w_om, wtb, wtbom);
  k_om<<<NB * (HW / 64), 256, 0, stream>>>(xt, wtbom, b_om, om);
  k_dcn<<<NB * (HW / 32), 256, 0, stream>>>(xt, om, wtb, bias, out);
}

// Round 5
// 149.819 us; speedup vs baseline: 1.9650x; 1.4340x over previous
//
#include <hip/hip_runtime.h>
#include <hip/hip_fp16.h>

// B=4, Cin=64, Cout=128, H=W=128, 3x3, stride=1, pad=1, dil=1
#define HW    16384
#define NB    4
#define CIN   64
#define COUT  128

typedef short  short8  __attribute__((ext_vector_type(8)));
typedef float  floatx4 __attribute__((ext_vector_type(4)));

// fp32 -> bf16 round-to-nearest-even (returns raw bits)
__device__ __forceinline__ unsigned short f2b(float f) {
  unsigned u = __float_as_uint(f);
  u += 0x7fff + ((u >> 16) & 1);
  return (unsigned short)(u >> 16);
}
__device__ __forceinline__ unsigned packbf2(float lo, float hi) {
  return (unsigned)f2b(lo) | ((unsigned)f2b(hi) << 16);
}
__device__ __forceinline__ float bflo(unsigned u) { return __uint_as_float(u << 16); }
__device__ __forceinline__ float bfhi(unsigned u) { return __uint_as_float(u & 0xffff0000u); }
__device__ __forceinline__ unsigned packh2(float a, float b) {
  __half2 h = __floats2half2_rn(a, b);
  return *(unsigned*)&h;
}

// ---------------------------------------------------------------------------
// k_tr: CHW fp32 -> HWC bf16, split tensors: xd[b][hw][64] (input_feat),
// xi[b][hw][64] (inter). Coalesced reads, padded LDS, uint4 stores with
// 8-lane-contiguous clusters.
// ---------------------------------------------------------------------------
__global__ __launch_bounds__(256) void k_tr(const float* __restrict__ x,
                                            const float* __restrict__ inter,
                                            short* __restrict__ xd,
                                            short* __restrict__ xi) {
  __shared__ unsigned sT[64][69];
  const int blk = blockIdx.x;
  const int b = blk >> 8, hw0 = (blk & 255) * 64;
  const int tid = threadIdx.x;
  const int px = tid & 63, cg = tid >> 6;
  const float* s0 = x     + (size_t)b * CIN * HW + hw0 + px;
  const float* s1 = inter + (size_t)b * CIN * HW + hw0 + px;
#pragma unroll
  for (int step = 0; step < 16; ++step) {
    int cp = step * 4 + cg;           // channel pair, c = 2*cp
    int c = cp * 2;
    const float* s = (c < 64) ? (s0 + c * HW) : (s1 + (c - 64) * HW);
    sT[px][cp] = packbf2(s[0], s[HW]);
  }
  __syncthreads();
  const int od = tid & 7, p0 = tid >> 3;    // 8 octets x 32 px
#pragma unroll
  for (int it = 0; it < 2; ++it) {
    int p = p0 + it * 32;
    uint4 a, bvec;
    a.x = sT[p][od * 4 + 0]; a.y = sT[p][od * 4 + 1];
    a.z = sT[p][od * 4 + 2]; a.w = sT[p][od * 4 + 3];
    bvec.x = sT[p][32 + od * 4 + 0]; bvec.y = sT[p][32 + od * 4 + 1];
    bvec.z = sT[p][32 + od * 4 + 2]; bvec.w = sT[p][32 + od * 4 + 3];
    size_t base = ((size_t)b * HW + hw0 + p) * 64 + od * 8;
    *(uint4*)(xd + base) = a;
    *(uint4*)(xi + base) = bvec;
  }
}

// ---------------------------------------------------------------------------
// k_prep: weights repacked into MFMA FRAGMENT ORDER so A-loads are 1KB
// contiguous per wave.
//  wtbF   [s18][wave4][tile2][quad4][l16][8]: weight[o=wv*32+t*16+l][k=s*32+q*8+i]
//         k -> c = k&63, tap = k>>6    (tap-major K, ck' = tap*64+c)
//  wtbomF [s36][tile2][quad4][l16][8]:  w_om[o=t*16+l][k=s*32+q*8+i]
//         k -> c = k&127, tap = k>>7   (o >= 27 zero-padded)
// ---------------------------------------------------------------------------
__global__ __launch_bounds__(256) void k_prep(const float* __restrict__ weight,
                                              const float* __restrict__ w_om,
                                              short* __restrict__ wtbF,
                                              short* __restrict__ wtbomF) {
  int i = blockIdx.x * 256 + threadIdx.x;
  if (i < 73728) {
    int i8 = i & 7, l = (i >> 3) & 15, q = (i >> 7) & 3;
    int t = (i >> 9) & 1, wv = (i >> 10) & 3, s = i >> 12;
    int o = wv * 32 + t * 16 + l;
    int k = s * 32 + q * 8 + i8;
    int c = k & 63, tap = k >> 6;
    wtbF[i] = (short)f2b(weight[o * 576 + c * 9 + tap]);
  }
  if (i < 36864) {
    int i8 = i & 7, l = (i >> 3) & 15, q = (i >> 7) & 3;
    int t = (i >> 9) & 1, s = i >> 10;
    int o = t * 16 + l;
    int k = s * 32 + q * 8 + i8;
    int c = k & 127, tap = k >> 7;
    wtbomF[i] = (o < 27) ? (short)f2b(w_om[o * 1152 + c * 9 + tap]) : (short)0;
  }
}

// ---------------------------------------------------------------------------
// k_om: 3x3 conv (Cin=128 concat, Cout=27) via halo patch + bf16 MFMA.
// Patch from xd/xi (HWC bf16): uint4 copies, 8-lane-contiguous clusters.
// A-operands stream from wtbomF: fully coalesced 1KB wave-loads.
// ---------------------------------------------------------------------------
__global__ __launch_bounds__(256) void k_om(const short* __restrict__ xd,
                                            const short* __restrict__ xi,
                                            const short* __restrict__ wtbomF,
                                            const float* __restrict__ b_om,
                                            float* __restrict__ om) {
  __shared__ __align__(16) short sP[16 * 198 * 8];   // 50688 B
  const int blk = blockIdx.x;
  const int b   = blk >> 8;
  const int hw0 = (blk & 255) * 64;
  const int h0  = hw0 >> 7;
  const int x0  = hw0 & 127;
  const int tid = threadIdx.x;
  const short* xdb = xd + (size_t)b * HW * 64;
  const short* xib = xi + (size_t)b * HW * 64;

  // ---- gather halo patch (3 rows x 66 cols x 128 ch), zero-padded ----
  for (int item = tid; item < 3168; item += 256) {   // lane: g fastest
    int g = item & 15, pxrow = item >> 4;
    int r3 = pxrow / 66, c66 = pxrow - r3 * 66;
    int y = h0 + r3 - 1;
    int x = x0 + c66 - 1;
    uint4 v = make_uint4(0, 0, 0, 0);
    if (((unsigned)y < 128u) && ((unsigned)x < 128u)) {
      const short* src = (g < 8)
          ? (xdb + (size_t)(y * 128 + x) * 64 + g * 8)
          : (xib + (size_t)(y * 128 + x) * 64 + (g - 8) * 8);
      v = *(const uint4*)src;
    }
    *(uint4*)(&sP[(g * 198 + pxrow) * 8]) = v;
  }
  __syncthreads();

  // ---- MFMA: M=32(o) x N=64(px) x K=1152, wave wv owns Ntile wv ----
  const int l15 = tid & 15, quad = (tid & 63) >> 4, wv = tid >> 6;
  const int afrag = (quad * 16 + l15) * 8;
  floatx4 acc0 = {0.f, 0.f, 0.f, 0.f};
  floatx4 acc1 = {0.f, 0.f, 0.f, 0.f};
  for (int tap = 0; tap < 9; ++tap) {
    int prow = (tap / 3) * 66 + (tap % 3) + wv * 16 + l15;   // tap-shifted px row
#pragma unroll
    for (int ss = 0; ss < 4; ++ss) {
      const short* aF = wtbomF + (size_t)(tap * 4 + ss) * 1024;
      short8 a0 = *(const short8*)(aF + afrag);
      short8 a1 = *(const short8*)(aF + 512 + afrag);
      short8 bb = *(const short8*)(&sP[((ss * 4 + quad) * 198 + prow) * 8]);
      acc0 = __builtin_amdgcn_mfma_f32_16x16x32_bf16(a0, bb, acc0, 0, 0, 0);
      acc1 = __builtin_amdgcn_mfma_f32_16x16x32_bf16(a1, bb, acc1, 0, 0, 0);
    }
  }

  // ---- epilogue: D[row=o][col=px], store o<27 ----
  float* ob = om + (size_t)b * 27 * HW + hw0 + wv * 16 + l15;
#pragma unroll
  for (int r = 0; r < 4; ++r) {
    int o = quad * 4 + r;
    if (o < 27) ob[o * HW] = acc0[r] + b_om[o];
    int o1 = 16 + quad * 4 + r;
    if (o1 < 27) ob[o1 * HW] = acc1[r] + b_om[o1];
  }
}

// ---------------------------------------------------------------------------
// k_dcn: modulated deformable conv, bf16 MFMA GEMM.
// Gather: thread (px=tid>>3, octet=tid&7): 8-lane clusters read contiguous
// 128B rows of xd -> ~16 lines/wave-load (was 64). sV layout [tap][px][c]
// with 72-short px stride (write contiguous, read 2-way max).
// A-operands stream from wtbF: coalesced 1KB wave-loads.
// ---------------------------------------------------------------------------
__global__ __launch_bounds__(256) void k_dcn(const short* __restrict__ xd,
                                             const float* __restrict__ om,
                                             const short* __restrict__ wtbF,
                                             const float* __restrict__ bias,
                                             float* __restrict__ out) {
  __shared__ __align__(16) short sV[9 * 32 * 72];   // 41472 B
  __shared__ unsigned sPar[9 * 32 * 3];             //  3456 B
  const int blk = blockIdx.x;
  const int b   = blk >> 9;
  const int hw0 = (blk & 511) * 32;
  const int tid = threadIdx.x;

  // ---- phase 0: packed bilinear params per (tap, px) ----
  for (int item = tid; item < 9 * 32; item += 256) {
    int k  = item >> 5;
    int px = item & 31;
    int hw = hw0 + px;
    int h = hw >> 7, w = hw & 127;
    const float* ob = om + (size_t)b * 27 * HW + hw;
    float dy = ob[(2 * k) * HW];
    float dx = ob[(2 * k + 1) * HW];
    float mr = ob[(18 + k) * HW];
    float m  = 1.f / (1.f + __expf(-mr));
    float py  = (float)(k / 3 - 1 + h) + dy;
    float pxx = (float)(k % 3 - 1 + w) + dx;
    float y0f = floorf(py), x0f = floorf(pxx);
    float fy = py - y0f, fx = pxx - x0f;
    int y0 = (int)y0f, x0 = (int)x0f;
    int y1 = y0 + 1, x1 = x0 + 1;
    float vy0 = ((unsigned)y0 < 128u) ? 1.f : 0.f;
    float vy1 = ((unsigned)y1 < 128u) ? 1.f : 0.f;
    float hx0 = ((unsigned)x0 < 128u) ? (1.f - fx) : 0.f;
    float hx1 = ((unsigned)x1 < 128u) ? fx : 0.f;
    int yc0 = min(max(y0, 0), 127), yc1 = min(max(y1, 0), 127);
    int xc0 = min(max(x0, 0), 127), xc1 = min(max(x1, 0), 127);
    int xb  = min(xc0, 126);
    float wA = (xc0 == xb     ? hx0 : 0.f) + (xc1 == xb     ? hx1 : 0.f);
    float wB = (xc0 == xb + 1 ? hx0 : 0.f) + (xc1 == xb + 1 ? hx1 : 0.f);
    float gy0 = (1.f - fy) * vy0 * m, gy1 = fy * vy1 * m;
    int base = (k * 32 + px) * 3;
    sPar[base + 0] = packh2(gy0 * wA, gy0 * wB);
    sPar[base + 1] = packh2(gy1 * wA, gy1 * wB);
    sPar[base + 2] = (unsigned)(yc0 * 128 + xb) | ((unsigned)(yc1 * 128 + xb) << 16);
  }
  __syncthreads();

  // ---- gather: 9 taps x 8 channels; 8-lane contiguous corner rows ----
  const int g0  = tid & 7;               // channel octet [0,8)
  const int px1 = tid >> 3;              // pixel [0,32)
  const short* xtb = xd + (size_t)b * HW * 64 + g0 * 8;

  unsigned pw0[9], pw1[9], pof[9];
#pragma unroll
  for (int j = 0; j < 9; ++j) {
    int base = (j * 32 + px1) * 3;
    pw0[j] = sPar[base + 0];
    pw1[j] = sPar[base + 1];
    pof[j] = sPar[base + 2];
  }

#pragma unroll 3
  for (int j = 0; j < 9; ++j) {
    float2 wy0 = __half22float2(*(__half2*)&pw0[j]);   // row y0: cols xb, xb+1
    float2 wy1 = __half22float2(*(__half2*)&pw1[j]);   // row y1
    int offA = pof[j] & 0xffff, offB = pof[j] >> 16;
    const short* pa = xtb + (size_t)offA * 64;
    const short* pb = xtb + (size_t)offB * 64;
    uint4 A  = *(const uint4*)pa;
    uint4 Bv = *(const uint4*)(pa + 64);
    uint4 C  = *(const uint4*)pb;
    uint4 D  = *(const uint4*)(pb + 64);
    unsigned res[4];
    const unsigned* Au = (const unsigned*)&A;
    const unsigned* Bu = (const unsigned*)&Bv;
    const unsigned* Cu = (const unsigned*)&C;
    const unsigned* Du = (const unsigned*)&D;
#pragma unroll
    for (int d = 0; d < 4; ++d) {
      float vlo = bflo(Au[d]) * wy0.x + bflo(Bu[d]) * wy0.y +
                  bflo(Cu[d]) * wy1.x + bflo(Du[d]) * wy1.y;
      float vhi = bfhi(Au[d]) * wy0.x + bfhi(Bu[d]) * wy0.y +
                  bfhi(Cu[d]) * wy1.x + bfhi(Du[d]) * wy1.y;
      res[d] = packbf2(vlo, vhi);
    }
    *(uint4*)(&sV[(j * 32 + px1) * 72 + g0 * 8]) =
        make_uint4(res[0], res[1], res[2], res[3]);
  }
  __syncthreads();

  // ---- MFMA: 18 K-steps, wave owns o [wave*32, wave*32+32) x 32 px ----
  const int l15 = tid & 15, quad = (tid & 63) >> 4, wave = tid >> 6;
  const int ob0 = wave * 32;
  const int afrag = (quad * 16 + l15) * 8;
  floatx4 acc00 = {0.f,0.f,0.f,0.f}, acc01 = {0.f,0.f,0.f,0.f};
  floatx4 acc10 = {0.f,0.f,0.f,0.f}, acc11 = {0.f,0.f,0.f,0.f};
#pragma unroll 6
  for (int s = 0; s < 18; ++s) {
    const short* aF = wtbF + (size_t)(s * 4 + wave) * 1024;
    short8 a0 = *(const short8*)(aF + afrag);
    short8 a1 = *(const short8*)(aF + 512 + afrag);
    int j = s >> 1, c0 = (s & 1) * 32 + quad * 8;
    short8 bb0 = *(const short8*)(&sV[(j * 32 + l15) * 72 + c0]);
    short8 bb1 = *(const short8*)(&sV[(j * 32 + 16 + l15) * 72 + c0]);
    acc00 = __builtin_amdgcn_mfma_f32_16x16x32_bf16(a0, bb0, acc00, 0, 0, 0);
    acc01 = __builtin_amdgcn_mfma_f32_16x16x32_bf16(a0, bb1, acc01, 0, 0, 0);
    acc10 = __builtin_amdgcn_mfma_f32_16x16x32_bf16(a1, bb0, acc10, 0, 0, 0);
    acc11 = __builtin_amdgcn_mfma_f32_16x16x32_bf16(a1, bb1, acc11, 0, 0, 0);
  }

  // ---- epilogue ----
  float* outb = out + (size_t)b * COUT * HW + hw0;
#pragma unroll
  for (int r = 0; r < 4; ++r) {
    int o = ob0 + quad * 4 + r;
    float bo = bias[o];
    outb[(size_t)o * HW + l15]      = acc00[r] + bo;
    outb[(size_t)o * HW + 16 + l15] = acc01[r] + bo;
    int o1 = o + 16;
    float bo1 = bias[o1];
    outb[(size_t)o1 * HW + l15]      = acc10[r] + bo1;
    outb[(size_t)o1 * HW + 16 + l15] = acc11[r] + bo1;
  }
}

// ---------------------------------------------------------------------------
extern "C" void kernel_launch(void* const* d_in, const int* in_sizes, int n_in,
                              void* d_out, int out_size, void* d_ws, size_t ws_size,
                              hipStream_t stream) {
  const float* input_feat = (const float*)d_in[0];  // [4,64,128,128]
  const float* inter      = (const float*)d_in[1];  // [4,64,128,128]
  const float* weight     = (const float*)d_in[2];  // [128,64,3,3]
  const float* bias       = (const float*)d_in[3];  // [128]
  const float* w_om       = (const float*)d_in[4];  // [27,128,3,3]
  const float* b_om       = (const float*)d_in[5];  // [27]
  float* out = (float*)d_out;                       // [4,128,128,128]

  float* om     = (float*)d_ws;                          // 7077888 B
  short* wtbF   = (short*)((char*)d_ws + 7077888);       // 147456 B
  short* wtbomF = (short*)((char*)d_ws + 7225344);       // 73728 B
  short* xd     = (short*)((char*)d_ws + 7299072);       // 8388608 B
  short* xi     = (short*)((char*)d_ws + 15687680);      // 8388608 B (23 MB total)

  k_tr<<<NB * (HW / 64), 256, 0, stream>>>(input_feat, inter, xd, xi);
  k_prep<<<288, 256, 0, stream>>>(weight, w_om, wtbF, wtbomF);
  k_om<<<NB * (HW / 64), 256, 0, stream>>>(xd, xi, wtbomF, b_om, om);
  k_dcn<<<NB * (HW / 32), 256, 0, stream>>>(xd, om, wtbF, bias, out);
}

// Round 6
// 134.966 us; speedup vs baseline: 2.1812x; 1.1101x over previous
//
#include <hip/hip_runtime.h>
#include <hip/hip_fp16.h>

// B=4, Cin=64, Cout=128, H=W=128, 3x3, stride=1, pad=1, dil=1
#define HW    16384
#define NB    4
#define CIN   64
#define COUT  128

typedef short  short8  __attribute__((ext_vector_type(8)));
typedef float  floatx4 __attribute__((ext_vector_type(4)));

__device__ __forceinline__ unsigned short f2b(float f) {
  unsigned u = __float_as_uint(f);
  u += 0x7fff + ((u >> 16) & 1);
  return (unsigned short)(u >> 16);
}
__device__ __forceinline__ unsigned packbf2(float lo, float hi) {
  return (unsigned)f2b(lo) | ((unsigned)f2b(hi) << 16);
}
__device__ __forceinline__ float bflo(unsigned u) { return __uint_as_float(u << 16); }
__device__ __forceinline__ float bfhi(unsigned u) { return __uint_as_float(u & 0xffff0000u); }
__device__ __forceinline__ unsigned packh2(float a, float b) {
  __half2 h = __floats2half2_rn(a, b);
  return *(unsigned*)&h;
}

// ---------------------------------------------------------------------------
// k_tr: CHW fp32 -> HWC bf16, split tensors xd[b][hw][64], xi[b][hw][64].
// ---------------------------------------------------------------------------
__global__ __launch_bounds__(256) void k_tr(const float* __restrict__ x,
                                            const float* __restrict__ inter,
                                            short* __restrict__ xd,
                                            short* __restrict__ xi) {
  __shared__ unsigned sT[64][69];
  const int blk = blockIdx.x;
  const int b = blk >> 8, hw0 = (blk & 255) * 64;
  const int tid = threadIdx.x;
  const int px = tid & 63, cg = tid >> 6;
  const float* s0 = x     + (size_t)b * CIN * HW + hw0 + px;
  const float* s1 = inter + (size_t)b * CIN * HW + hw0 + px;
#pragma unroll
  for (int step = 0; step < 16; ++step) {
    int cp = step * 4 + cg;
    int c = cp * 2;
    const float* s = (c < 64) ? (s0 + c * HW) : (s1 + (c - 64) * HW);
    sT[px][cp] = packbf2(s[0], s[HW]);
  }
  __syncthreads();
  const int od = tid & 7, p0 = tid >> 3;
#pragma unroll
  for (int it = 0; it < 2; ++it) {
    int p = p0 + it * 32;
    uint4 a, bvec;
    a.x = sT[p][od * 4 + 0]; a.y = sT[p][od * 4 + 1];
    a.z = sT[p][od * 4 + 2]; a.w = sT[p][od * 4 + 3];
    bvec.x = sT[p][32 + od * 4 + 0]; bvec.y = sT[p][32 + od * 4 + 1];
    bvec.z = sT[p][32 + od * 4 + 2]; bvec.w = sT[p][32 + od * 4 + 3];
    size_t base = ((size_t)b * HW + hw0 + p) * 64 + od * 8;
    *(uint4*)(xd + base) = a;
    *(uint4*)(xi + base) = bvec;
  }
}

// ---------------------------------------------------------------------------
// k_prep: weights in MFMA FRAGMENT ORDER (1KB-contiguous wave loads).
//  wtbF   [s18][wave4][tile2][quad4][l16][8] ; k = s*32+q*8+i, c=k&63, tap=k>>6
//  wtbomF [s36][tile2][quad4][l16][8]        ; k = s*32+q*8+i, c=k&127, tap=k>>7
// ---------------------------------------------------------------------------
__global__ __launch_bounds__(256) void k_prep(const float* __restrict__ weight,
                                              const float* __restrict__ w_om,
                                              short* __restrict__ wtbF,
                                              short* __restrict__ wtbomF) {
  int i = blockIdx.x * 256 + threadIdx.x;
  if (i < 73728) {
    int i8 = i & 7, l = (i >> 3) & 15, q = (i >> 7) & 3;
    int t = (i >> 9) & 1, wv = (i >> 10) & 3, s = i >> 12;
    int o = wv * 32 + t * 16 + l;
    int k = s * 32 + q * 8 + i8;
    int c = k & 63, tap = k >> 6;
    wtbF[i] = (short)f2b(weight[o * 576 + c * 9 + tap]);
  }
  if (i < 36864) {
    int i8 = i & 7, l = (i >> 3) & 15, q = (i >> 7) & 3;
    int t = (i >> 9) & 1, s = i >> 10;
    int o = t * 16 + l;
    int k = s * 32 + q * 8 + i8;
    int c = k & 127, tap = k >> 7;
    wtbomF[i] = (o < 27) ? (short)f2b(w_om[o * 1152 + c * 9 + tap]) : (short)0;
  }
}

// ---------------------------------------------------------------------------
// k_dcn: FUSED offset/mask conv + modulated deformable conv.
// Block = 256 thr, 32-px row-segment tile.
//  A: halo 3x34x128ch (xd++xi) -> LDS [g16][prow102][8]  (26112 B)
//  B: om GEMM M=32 x N=32 x K=1152, K split across 4 waves (9 steps each),
//     partial D tiles -> LDS [w4][32r][32c] f32 (16384 B), reduce (+b_om)
//  C: bilinear params from reduced tile -> sPar (3456 B)
//  D: gather 9 taps x 8ch/thread from xd -> sV [tap*32+px][72] bf16 (41472 B,
//     overlays A/B regions)
//  E: main GEMM M=128 x N=32 x K=576 (18 steps), fragment-order A
// ---------------------------------------------------------------------------
__global__ __launch_bounds__(256) void k_dcn(const short* __restrict__ xd,
                                             const short* __restrict__ xi,
                                             const short* __restrict__ wtbF,
                                             const short* __restrict__ wtbomF,
                                             const float* __restrict__ b_om,
                                             const float* __restrict__ bias,
                                             float* __restrict__ out) {
  __shared__ __align__(16) char smem[45952];
  short*    sH    = (short*)smem;               // halo, then overlaid by sV
  float*    sPart = (float*)(smem + 26112);     // om partials [4][32][32]
  short*    sV    = (short*)smem;               // gathered V panel
  unsigned* sPar  = (unsigned*)(smem + 42496);  // packed bilinear params

  const int blk = blockIdx.x;
  const int b   = blk >> 9;
  const int hw0 = (blk & 511) * 32;
  const int h0  = hw0 >> 7;
  const int x0  = hw0 & 127;
  const int tid = threadIdx.x;
  const int l15 = tid & 15, quad = (tid & 63) >> 4, wave = tid >> 6;

  const short* xdb = xd + (size_t)b * HW * 64;
  const short* xib = xi + (size_t)b * HW * 64;

  // ---- phase A: halo patch 3 rows x 34 cols x 128 ch ----
  for (int item = tid; item < 1632; item += 256) {
    int g = item & 15, prow = item >> 4;        // prow = r3*34 + c34
    int r3 = prow / 34, c34 = prow - r3 * 34;
    int y = h0 + r3 - 1;
    int x = x0 + c34 - 1;
    uint4 v = make_uint4(0, 0, 0, 0);
    if (((unsigned)y < 128u) && ((unsigned)x < 128u)) {
      const short* src = (g < 8)
          ? (xdb + (size_t)(y * 128 + x) * 64 + g * 8)
          : (xib + (size_t)(y * 128 + x) * 64 + (g - 8) * 8);
      v = *(const uint4*)src;
    }
    *(uint4*)(&sH[(g * 102 + prow) * 8]) = v;
  }
  __syncthreads();

  // ---- phase B: om GEMM, wave w handles K-steps s = w, w+4, ..., w+32 ----
  {
    floatx4 oa = {0.f,0.f,0.f,0.f}, ob_ = {0.f,0.f,0.f,0.f};
    floatx4 oc = {0.f,0.f,0.f,0.f}, od = {0.f,0.f,0.f,0.f};
#pragma unroll
    for (int i = 0; i < 9; ++i) {
      int s = wave + i * 4;                     // [0,36)
      int tap = s >> 2;
      int ty = tap / 3, tx = tap % 3;
      int g = (s * 4 + quad) & 15;
      const short* aF = wtbomF + (size_t)s * 1024 + (quad * 16 + l15) * 8;
      short8 a0 = *(const short8*)aF;
      short8 a1 = *(const short8*)(aF + 512);
      int pb = (g * 102 + ty * 34 + tx) * 8;
      short8 b0 = *(const short8*)(&sH[pb + l15 * 8]);
      short8 b1 = *(const short8*)(&sH[pb + (16 + l15) * 8]);
      oa  = __builtin_amdgcn_mfma_f32_16x16x32_bf16(a0, b0, oa , 0, 0, 0);
      ob_ = __builtin_amdgcn_mfma_f32_16x16x32_bf16(a0, b1, ob_, 0, 0, 0);
      oc  = __builtin_amdgcn_mfma_f32_16x16x32_bf16(a1, b0, oc , 0, 0, 0);
      od  = __builtin_amdgcn_mfma_f32_16x16x32_bf16(a1, b1, od , 0, 0, 0);
    }
    float* pw = sPart + wave * 1024;
#pragma unroll
    for (int r = 0; r < 4; ++r) {
      int row = quad * 4 + r;
      pw[row * 32 + l15]             = oa[r];
      pw[row * 32 + 16 + l15]        = ob_[r];
      pw[(16 + row) * 32 + l15]      = oc[r];
      pw[(16 + row) * 32 + 16 + l15] = od[r];
    }
  }
  __syncthreads();

  // ---- reduce partials (+ b_om) into sPart[0] ----
  for (int idx = tid; idx < 1024; idx += 256) {
    float v = sPart[idx] + sPart[1024 + idx] + sPart[2048 + idx] + sPart[3072 + idx];
    int r = idx >> 5;
    sPart[idx] = v + ((r < 27) ? b_om[r] : 0.f);
  }
  __syncthreads();

  // ---- phase C: packed bilinear params per (tap, px) ----
  for (int item = tid; item < 288; item += 256) {
    int k  = item >> 5;
    int px = item & 31;
    float dy = sPart[(2 * k) * 32 + px];
    float dx = sPart[(2 * k + 1) * 32 + px];
    float mr = sPart[(18 + k) * 32 + px];
    int h = h0, w = x0 + px;
    float m  = 1.f / (1.f + __expf(-mr));
    float py  = (float)(k / 3 - 1 + h) + dy;
    float pxx = (float)(k % 3 - 1 + w) + dx;
    float y0f = floorf(py), x0f = floorf(pxx);
    float fy = py - y0f, fx = pxx - x0f;
    int y0 = (int)y0f, x0c = (int)x0f;
    int y1 = y0 + 1, x1 = x0c + 1;
    float vy0 = ((unsigned)y0 < 128u) ? 1.f : 0.f;
    float vy1 = ((unsigned)y1 < 128u) ? 1.f : 0.f;
    float hx0 = ((unsigned)x0c < 128u) ? (1.f - fx) : 0.f;
    float hx1 = ((unsigned)x1 < 128u) ? fx : 0.f;
    int yc0 = min(max(y0, 0), 127), yc1 = min(max(y1, 0), 127);
    int xc0 = min(max(x0c, 0), 127), xc1 = min(max(x1, 0), 127);
    int xb  = min(xc0, 126);
    float wA = (xc0 == xb     ? hx0 : 0.f) + (xc1 == xb     ? hx1 : 0.f);
    float wB = (xc0 == xb + 1 ? hx0 : 0.f) + (xc1 == xb + 1 ? hx1 : 0.f);
    float gy0 = (1.f - fy) * vy0 * m, gy1 = fy * vy1 * m;
    int base = (k * 32 + px) * 3;
    sPar[base + 0] = packh2(gy0 * wA, gy0 * wB);
    sPar[base + 1] = packh2(gy1 * wA, gy1 * wB);
    sPar[base + 2] = (unsigned)(yc0 * 128 + xb) | ((unsigned)(yc1 * 128 + xb) << 16);
  }
  __syncthreads();

  // ---- phase D: gather 9 taps x 8ch/thread (overlays halo/partials) ----
  const int g0  = tid & 7;
  const int px1 = tid >> 3;
  const short* xtb = xdb + g0 * 8;

  unsigned pw0[9], pw1[9], pof[9];
#pragma unroll
  for (int j = 0; j < 9; ++j) {
    int base = (j * 32 + px1) * 3;
    pw0[j] = sPar[base + 0];
    pw1[j] = sPar[base + 1];
    pof[j] = sPar[base + 2];
  }

#pragma unroll 3
  for (int j = 0; j < 9; ++j) {
    float2 wy0 = __half22float2(*(__half2*)&pw0[j]);
    float2 wy1 = __half22float2(*(__half2*)&pw1[j]);
    int offA = pof[j] & 0xffff, offB = pof[j] >> 16;
    const short* pa = xtb + (size_t)offA * 64;
    const short* pb = xtb + (size_t)offB * 64;
    uint4 A  = *(const uint4*)pa;
    uint4 Bv = *(const uint4*)(pa + 64);
    uint4 C  = *(const uint4*)pb;
    uint4 D  = *(const uint4*)(pb + 64);
    unsigned res[4];
    const unsigned* Au = (const unsigned*)&A;
    const unsigned* Bu = (const unsigned*)&Bv;
    const unsigned* Cu = (const unsigned*)&C;
    const unsigned* Du = (const unsigned*)&D;
#pragma unroll
    for (int d = 0; d < 4; ++d) {
      float vlo = bflo(Au[d]) * wy0.x + bflo(Bu[d]) * wy0.y +
                  bflo(Cu[d]) * wy1.x + bflo(Du[d]) * wy1.y;
      float vhi = bfhi(Au[d]) * wy0.x + bfhi(Bu[d]) * wy0.y +
                  bfhi(Cu[d]) * wy1.x + bfhi(Du[d]) * wy1.y;
      res[d] = packbf2(vlo, vhi);
    }
    *(uint4*)(&sV[(j * 32 + px1) * 72 + g0 * 8]) =
        make_uint4(res[0], res[1], res[2], res[3]);
  }
  __syncthreads();

  // ---- phase E: main GEMM, 18 K-steps ----
  const int ob0 = wave * 32;
  const int afrag = (quad * 16 + l15) * 8;
  floatx4 acc00 = {0.f,0.f,0.f,0.f}, acc01 = {0.f,0.f,0.f,0.f};
  floatx4 acc10 = {0.f,0.f,0.f,0.f}, acc11 = {0.f,0.f,0.f,0.f};
#pragma unroll 6
  for (int s = 0; s < 18; ++s) {
    const short* aF = wtbF + (size_t)(s * 4 + wave) * 1024;
    short8 a0 = *(const short8*)(aF + afrag);
    short8 a1 = *(const short8*)(aF + 512 + afrag);
    int j = s >> 1, c0 = (s & 1) * 32 + quad * 8;
    short8 bb0 = *(const short8*)(&sV[(j * 32 + l15) * 72 + c0]);
    short8 bb1 = *(const short8*)(&sV[(j * 32 + 16 + l15) * 72 + c0]);
    acc00 = __builtin_amdgcn_mfma_f32_16x16x32_bf16(a0, bb0, acc00, 0, 0, 0);
    acc01 = __builtin_amdgcn_mfma_f32_16x16x32_bf16(a0, bb1, acc01, 0, 0, 0);
    acc10 = __builtin_amdgcn_mfma_f32_16x16x32_bf16(a1, bb0, acc10, 0, 0, 0);
    acc11 = __builtin_amdgcn_mfma_f32_16x16x32_bf16(a1, bb1, acc11, 0, 0, 0);
  }

  // ---- epilogue ----
  float* outb = out + (size_t)b * COUT * HW + hw0;
#pragma unroll
  for (int r = 0; r < 4; ++r) {
    int o = ob0 + quad * 4 + r;
    float bo = bias[o];
    outb[(size_t)o * HW + l15]      = acc00[r] + bo;
    outb[(size_t)o * HW + 16 + l15] = acc01[r] + bo;
    int o1 = o + 16;
    float bo1 = bias[o1];
    outb[(size_t)o1 * HW + l15]      = acc10[r] + bo1;
    outb[(size_t)o1 * HW + 16 + l15] = acc11[r] + bo1;
  }
}

// ---------------------------------------------------------------------------
extern "C" void kernel_launch(void* const* d_in, const int* in_sizes, int n_in,
                              void* d_out, int out_size, void* d_ws, size_t ws_size,
                              hipStream_t stream) {
  const float* input_feat = (const float*)d_in[0];  // [4,64,128,128]
  const float* inter      = (const float*)d_in[1];  // [4,64,128,128]
  const float* weight     = (const float*)d_in[2];  // [128,64,3,3]
  const float* bias       = (const float*)d_in[3];  // [128]
  const float* w_om       = (const float*)d_in[4];  // [27,128,3,3]
  const float* b_om       = (const float*)d_in[5];  // [27]
  float* out = (float*)d_out;                       // [4,128,128,128]

  short* wtbF   = (short*)d_ws;                          // 147456 B
  short* wtbomF = (short*)((char*)d_ws + 147456);        // 73728 B
  short* xd     = (short*)((char*)d_ws + 221184);        // 8388608 B
  short* xi     = (short*)((char*)d_ws + 8609792);       // 8388608 B (~17 MB)

  k_tr<<<NB * (HW / 64), 256, 0, stream>>>(input_feat, inter, xd, xi);
  k_prep<<<288, 256, 0, stream>>>(weight, w_om, wtbF, wtbomF);
  k_dcn<<<NB * (HW / 32), 256, 0, stream>>>(xd, xi, wtbF, wtbomF, b_om, bias, out);
}

// Round 7
// 131.953 us; speedup vs baseline: 2.2311x; 1.0228x over previous
//
#include <hip/hip_runtime.h>
#include <hip/hip_fp16.h>

// B=4, Cin=64, Cout=128, H=W=128, 3x3, stride=1, pad=1, dil=1
#define HW    16384
#define NB    4
#define CIN   64
#define COUT  128

typedef short  short8  __attribute__((ext_vector_type(8)));
typedef float  floatx4 __attribute__((ext_vector_type(4)));

__device__ __forceinline__ unsigned short f2b(float f) {
  unsigned u = __float_as_uint(f);
  u += 0x7fff + ((u >> 16) & 1);
  return (unsigned short)(u >> 16);
}
__device__ __forceinline__ unsigned packbf2(float lo, float hi) {
  return (unsigned)f2b(lo) | ((unsigned)f2b(hi) << 16);
}
__device__ __forceinline__ float bflo(unsigned u) { return __uint_as_float(u << 16); }
__device__ __forceinline__ float bfhi(unsigned u) { return __uint_as_float(u & 0xffff0000u); }
__device__ __forceinline__ unsigned packh2(float a, float b) {
  __half2 h = __floats2half2_rn(a, b);
  return *(unsigned*)&h;
}

// ---------------------------------------------------------------------------
// k_tr: CHW fp32 -> HWC bf16 (xd=input_feat, xi=inter) + fused weight prep.
//  wtbF   [s18][wave4][tile2][quad4][l16][8] ; k=s*32+q*8+i, c=k&63,  tap=k>>6
//  wtbomF [s36][tile2][quad4][l16][8]        ; k=s*32+q*8+i, c=k&127, tap=k>>7
// ---------------------------------------------------------------------------
__global__ __launch_bounds__(256) void k_tr(const float* __restrict__ x,
                                            const float* __restrict__ inter,
                                            const float* __restrict__ weight,
                                            const float* __restrict__ w_om,
                                            short* __restrict__ xd,
                                            short* __restrict__ xi,
                                            short* __restrict__ wtbF,
                                            short* __restrict__ wtbomF) {
  __shared__ unsigned sT[64][69];
  const int blk = blockIdx.x;
  const int b = blk >> 8, hw0 = (blk & 255) * 64;
  const int tid = threadIdx.x;
  const int px = tid & 63, cg = tid >> 6;
  const float* s0 = x     + (size_t)b * CIN * HW + hw0 + px;
  const float* s1 = inter + (size_t)b * CIN * HW + hw0 + px;
#pragma unroll
  for (int step = 0; step < 16; ++step) {
    int cp = step * 4 + cg;
    int c = cp * 2;
    const float* s = (c < 64) ? (s0 + c * HW) : (s1 + (c - 64) * HW);
    sT[px][cp] = packbf2(s[0], s[HW]);
  }
  // fused weight prep while LDS settles
  {
    int i = blk * 256 + tid;
    if (i < 73728) {
      int i8 = i & 7, l = (i >> 3) & 15, q = (i >> 7) & 3;
      int t = (i >> 9) & 1, wv = (i >> 10) & 3, s = i >> 12;
      int o = wv * 32 + t * 16 + l;
      int k = s * 32 + q * 8 + i8;
      int c = k & 63, tap = k >> 6;
      wtbF[i] = (short)f2b(weight[o * 576 + c * 9 + tap]);
    }
    if (i < 36864) {
      int i8 = i & 7, l = (i >> 3) & 15, q = (i >> 7) & 3;
      int t = (i >> 9) & 1, s = i >> 10;
      int o = t * 16 + l;
      int k = s * 32 + q * 8 + i8;
      int c = k & 127, tap = k >> 7;
      wtbomF[i] = (o < 27) ? (short)f2b(w_om[o * 1152 + c * 9 + tap]) : (short)0;
    }
  }
  __syncthreads();
  const int od = tid & 7, p0 = tid >> 3;
#pragma unroll
  for (int it = 0; it < 2; ++it) {
    int p = p0 + it * 32;
    uint4 a, bvec;
    a.x = sT[p][od * 4 + 0]; a.y = sT[p][od * 4 + 1];
    a.z = sT[p][od * 4 + 2]; a.w = sT[p][od * 4 + 3];
    bvec.x = sT[p][32 + od * 4 + 0]; bvec.y = sT[p][32 + od * 4 + 1];
    bvec.z = sT[p][32 + od * 4 + 2]; bvec.w = sT[p][32 + od * 4 + 3];
    size_t base = ((size_t)b * HW + hw0 + p) * 64 + od * 8;
    *(uint4*)(xd + base) = a;
    *(uint4*)(xi + base) = bvec;
  }
}

// ---------------------------------------------------------------------------
// k_dcn: FUSED offset/mask conv + modulated deformable conv. 32-px tile.
// LDS (36864 B total -> 4 blocks/CU):
//  sH    @0      halo 3x34x128ch bf16            26112 B (live A->B)
//  sPart @26112  om partials [kh2][27r][32c] f32  6912 B (live B->C)
//  sPar  @33024  packed bilinear params           3456 B (live C->preload)
//  sV    @0      V panel [tap*32+px][64] XOR-swz 36864 B (live D->E)
// Phase B: om GEMM M=32 N=32 K=1152, waves split K(2) x N(2), 36 MFMA each.
// Phase E: main GEMM M=128 N=32 K=576, 18 steps, fragment-order A.
// ---------------------------------------------------------------------------
__global__ __launch_bounds__(256, 4) void k_dcn(const short* __restrict__ xd,
                                                const short* __restrict__ xi,
                                                const short* __restrict__ wtbF,
                                                const short* __restrict__ wtbomF,
                                                const float* __restrict__ b_om,
                                                const float* __restrict__ bias,
                                                float* __restrict__ out) {
  __shared__ __align__(16) char smem[36864];
  short*    sH    = (short*)smem;
  float*    sPart = (float*)(smem + 26112);
  unsigned* sPar  = (unsigned*)(smem + 33024);
  short*    sV    = (short*)smem;

  const int blk = blockIdx.x;
  const int b   = blk >> 9;
  const int hw0 = (blk & 511) * 32;
  const int h0  = hw0 >> 7;
  const int x0  = hw0 & 127;
  const int tid = threadIdx.x;
  const int l15 = tid & 15, quad = (tid & 63) >> 4, wave = tid >> 6;

  const short* xdb = xd + (size_t)b * HW * 64;
  const short* xib = xi + (size_t)b * HW * 64;

  // ---- phase A: halo patch 3 rows x 34 cols x 128 ch ----
  for (int item = tid; item < 1632; item += 256) {
    int g = item & 15, prow = item >> 4;        // prow = r3*34 + c34
    int r3 = prow / 34, c34 = prow - r3 * 34;
    int y = h0 + r3 - 1;
    int x = x0 + c34 - 1;
    uint4 v = make_uint4(0, 0, 0, 0);
    if (((unsigned)y < 128u) && ((unsigned)x < 128u)) {
      const short* src = (g < 8)
          ? (xdb + (size_t)(y * 128 + x) * 64 + g * 8)
          : (xib + (size_t)(y * 128 + x) * 64 + (g - 8) * 8);
      v = *(const uint4*)src;
    }
    *(uint4*)(&sH[(g * 102 + prow) * 8]) = v;
  }
  __syncthreads();

  // ---- phase B: om GEMM, wave = (kh = wave>>1) x (nh = wave&1) ----
  {
    const int kh = wave >> 1, nh = wave & 1;
    floatx4 oa = {0.f,0.f,0.f,0.f}, oc = {0.f,0.f,0.f,0.f};
#pragma unroll
    for (int i = 0; i < 18; ++i) {
      int s = kh * 18 + i;                      // [0,36)
      int tap = s >> 2;
      int ty = tap / 3, tx = tap % 3;
      int g = (s * 4 + quad) & 15;
      const short* aF = wtbomF + (size_t)s * 1024 + (quad * 16 + l15) * 8;
      short8 a0 = *(const short8*)aF;
      short8 a1 = *(const short8*)(aF + 512);
      short8 bb = *(const short8*)(&sH[(g * 102 + ty * 34 + tx + nh * 16 + l15) * 8]);
      oa = __builtin_amdgcn_mfma_f32_16x16x32_bf16(a0, bb, oa, 0, 0, 0);
      oc = __builtin_amdgcn_mfma_f32_16x16x32_bf16(a1, bb, oc, 0, 0, 0);
    }
    float* pw = sPart + kh * 864 + nh * 16 + l15;
#pragma unroll
    for (int r = 0; r < 4; ++r) {
      int row0 = quad * 4 + r;                  // tile 0 rows: 0..15
      pw[row0 * 32] = oa[r];
      int row1 = 16 + quad * 4 + r;             // tile 1 rows: 16..31
      if (row1 < 27) pw[row1 * 32] = oc[r];
    }
  }
  __syncthreads();

  // ---- phase C: bilinear params (reduce K-halves + b_om inline) ----
  for (int item = tid; item < 288; item += 256) {
    int k  = item >> 5;
    int px = item & 31;
    float dy = sPart[(2 * k) * 32 + px]     + sPart[864 + (2 * k) * 32 + px]     + b_om[2 * k];
    float dx = sPart[(2 * k + 1) * 32 + px] + sPart[864 + (2 * k + 1) * 32 + px] + b_om[2 * k + 1];
    float mr = sPart[(18 + k) * 32 + px]    + sPart[864 + (18 + k) * 32 + px]    + b_om[18 + k];
    int h = h0, w = x0 + px;
    float m  = 1.f / (1.f + __expf(-mr));
    float py  = (float)(k / 3 - 1 + h) + dy;
    float pxx = (float)(k % 3 - 1 + w) + dx;
    float y0f = floorf(py), x0f = floorf(pxx);
    float fy = py - y0f, fx = pxx - x0f;
    int y0 = (int)y0f, x0c = (int)x0f;
    int y1 = y0 + 1, x1 = x0c + 1;
    float vy0 = ((unsigned)y0 < 128u) ? 1.f : 0.f;
    float vy1 = ((unsigned)y1 < 128u) ? 1.f : 0.f;
    float hx0 = ((unsigned)x0c < 128u) ? (1.f - fx) : 0.f;
    float hx1 = ((unsigned)x1 < 128u) ? fx : 0.f;
    int yc0 = min(max(y0, 0), 127), yc1 = min(max(y1, 0), 127);
    int xc0 = min(max(x0c, 0), 127), xc1 = min(max(x1, 0), 127);
    int xb  = min(xc0, 126);
    float wA = (xc0 == xb     ? hx0 : 0.f) + (xc1 == xb     ? hx1 : 0.f);
    float wB = (xc0 == xb + 1 ? hx0 : 0.f) + (xc1 == xb + 1 ? hx1 : 0.f);
    float gy0 = (1.f - fy) * vy0 * m, gy1 = fy * vy1 * m;
    int base = (k * 32 + px) * 3;
    sPar[base + 0] = packh2(gy0 * wA, gy0 * wB);
    sPar[base + 1] = packh2(gy1 * wA, gy1 * wB);
    sPar[base + 2] = (unsigned)(yc0 * 128 + xb) | ((unsigned)(yc1 * 128 + xb) << 16);
  }
  __syncthreads();

  // ---- preload params to regs (sV will overwrite sPar region) ----
  const int g0  = tid & 7;
  const int px1 = tid >> 3;
  unsigned pw0[9], pw1[9], pof[9];
#pragma unroll
  for (int j = 0; j < 9; ++j) {
    int base = (j * 32 + px1) * 3;
    pw0[j] = sPar[base + 0];
    pw1[j] = sPar[base + 1];
    pof[j] = sPar[base + 2];
  }
  __syncthreads();

  // ---- phase D: gather 9 taps x 8ch/thread, XOR-swizzled sV ----
  const short* xtb = xdb + g0 * 8;
  const int slot = (g0 ^ (px1 & 7)) * 8;
#pragma unroll 3
  for (int j = 0; j < 9; ++j) {
    float2 wy0 = __half22float2(*(__half2*)&pw0[j]);
    float2 wy1 = __half22float2(*(__half2*)&pw1[j]);
    int offA = pof[j] & 0xffff, offB = pof[j] >> 16;
    const short* pa = xtb + (size_t)offA * 64;
    const short* pb = xtb + (size_t)offB * 64;
    uint4 A  = *(const uint4*)pa;
    uint4 Bv = *(const uint4*)(pa + 64);
    uint4 C  = *(const uint4*)pb;
    uint4 D  = *(const uint4*)(pb + 64);
    unsigned res[4];
    const unsigned* Au = (const unsigned*)&A;
    const unsigned* Bu = (const unsigned*)&Bv;
    const unsigned* Cu = (const unsigned*)&C;
    const unsigned* Du = (const unsigned*)&D;
#pragma unroll
    for (int d = 0; d < 4; ++d) {
      float vlo = bflo(Au[d]) * wy0.x + bflo(Bu[d]) * wy0.y +
                  bflo(Cu[d]) * wy1.x + bflo(Du[d]) * wy1.y;
      float vhi = bfhi(Au[d]) * wy0.x + bfhi(Bu[d]) * wy0.y +
                  bfhi(Cu[d]) * wy1.x + bfhi(Du[d]) * wy1.y;
      res[d] = packbf2(vlo, vhi);
    }
    *(uint4*)(&sV[(j * 32 + px1) * 64 + slot]) =
        make_uint4(res[0], res[1], res[2], res[3]);
  }
  __syncthreads();

  // ---- phase E: main GEMM, 18 K-steps, swizzled B reads ----
  const int ob0 = wave * 32;
  const int afrag = (quad * 16 + l15) * 8;
  const int xkey = (l15 & 7);
  floatx4 acc00 = {0.f,0.f,0.f,0.f}, acc01 = {0.f,0.f,0.f,0.f};
  floatx4 acc10 = {0.f,0.f,0.f,0.f}, acc11 = {0.f,0.f,0.f,0.f};
#pragma unroll 6
  for (int s = 0; s < 18; ++s) {
    const short* aF = wtbF + (size_t)(s * 4 + wave) * 1024;
    short8 a0 = *(const short8*)(aF + afrag);
    short8 a1 = *(const short8*)(aF + 512 + afrag);
    int j = s >> 1;
    int oct = ((s & 1) * 4 + quad) ^ xkey;      // swizzled octet slot
    short8 bb0 = *(const short8*)(&sV[(j * 32 + l15) * 64 + oct * 8]);
    short8 bb1 = *(const short8*)(&sV[(j * 32 + 16 + l15) * 64 + oct * 8]);
    acc00 = __builtin_amdgcn_mfma_f32_16x16x32_bf16(a0, bb0, acc00, 0, 0, 0);
    acc01 = __builtin_amdgcn_mfma_f32_16x16x32_bf16(a0, bb1, acc01, 0, 0, 0);
    acc10 = __builtin_amdgcn_mfma_f32_16x16x32_bf16(a1, bb0, acc10, 0, 0, 0);
    acc11 = __builtin_amdgcn_mfma_f32_16x16x32_bf16(a1, bb1, acc11, 0, 0, 0);
  }

  // ---- epilogue ----
  float* outb = out + (size_t)b * COUT * HW + hw0;
#pragma unroll
  for (int r = 0; r < 4; ++r) {
    int o = ob0 + quad * 4 + r;
    float bo = bias[o];
    outb[(size_t)o * HW + l15]      = acc00[r] + bo;
    outb[(size_t)o * HW + 16 + l15] = acc01[r] + bo;
    int o1 = o + 16;
    float bo1 = bias[o1];
    outb[(size_t)o1 * HW + l15]      = acc10[r] + bo1;
    outb[(size_t)o1 * HW + 16 + l15] = acc11[r] + bo1;
  }
}

// ---------------------------------------------------------------------------
extern "C" void kernel_launch(void* const* d_in, const int* in_sizes, int n_in,
                              void* d_out, int out_size, void* d_ws, size_t ws_size,
                              hipStream_t stream) {
  const float* input_feat = (const float*)d_in[0];  // [4,64,128,128]
  const float* inter      = (const float*)d_in[1];  // [4,64,128,128]
  const float* weight     = (const float*)d_in[2];  // [128,64,3,3]
  const float* bias       = (const float*)d_in[3];  // [128]
  const float* w_om       = (const float*)d_in[4];  // [27,128,3,3]
  const float* b_om       = (const float*)d_in[5];  // [27]
  float* out = (float*)d_out;                       // [4,128,128,128]

  short* wtbF   = (short*)d_ws;                          // 147456 B
  short* wtbomF = (short*)((char*)d_ws + 147456);        // 73728 B
  short* xd     = (short*)((char*)d_ws + 221184);        // 8388608 B
  short* xi     = (short*)((char*)d_ws + 8609792);       // 8388608 B (~17 MB)

  k_tr<<<NB * (HW / 64), 256, 0, stream>>>(input_feat, inter, weight, w_om,
                                           xd, xi, wtbF, wtbomF);
  k_dcn<<<NB * (HW / 32), 256, 0, stream>>>(xd, xi, wtbF, wtbomF, b_om, bias, out);
}